// Round 1
// baseline (998.577 us; speedup 1.0000x reference)
//
#include <hip/hip_runtime.h>

#define N_NODES 100000
#define N_EDGES 1600000
#define D_IN    256
#define D_HID   64
#define D_OUT   32
#define NPROP   10

#define SCAN_T 256
#define SCAN_E 8
#define SCAN_B (SCAN_T * SCAN_E)   // 2048 elements per scan block
#define NB1 ((N_NODES + SCAN_B - 1) / SCAN_B)  // 49

// ---------------- MLP head: x0 = relu(F@W1 + b1) @ W2 + b2 ----------------
// One thread per node. Feature row read as float4 (per-thread contiguous,
// full-cacheline). All W1/W2/b1/b2 indices are wave-uniform -> scalar loads.
__global__ __launch_bounds__(256) void mlp_kernel(
    const float* __restrict__ F, const float* __restrict__ W1,
    const float* __restrict__ b1, const float* __restrict__ W2,
    const float* __restrict__ b2, float* __restrict__ x0)
{
  int t = threadIdx.x;
  int n = blockIdx.x * 256 + t;
  int nc = n < N_NODES ? n : N_NODES - 1;
  const float4* frow = (const float4*)(F + (size_t)nc * D_IN);

  float h[D_HID];
#pragma unroll
  for (int j = 0; j < D_HID; ++j) h[j] = 0.f;

  // keep outer loop rolled: 256 FMAs per body, code stays icache-friendly
#pragma unroll 1
  for (int k4 = 0; k4 < D_IN / 4; ++k4) {
    float4 f4 = frow[k4];
    float fs[4] = {f4.x, f4.y, f4.z, f4.w};
#pragma unroll
    for (int u = 0; u < 4; ++u) {
      const float* wrow = W1 + (size_t)(k4 * 4 + u) * D_HID;  // uniform
#pragma unroll
      for (int j = 0; j < D_HID; ++j) h[j] = fmaf(fs[u], wrow[j], h[j]);
    }
  }

#pragma unroll
  for (int j = 0; j < D_HID; ++j) h[j] = fmaxf(h[j] + b1[j], 0.f);

  // layer 2: 4 outputs at a time, store float4
#pragma unroll 1
  for (int og = 0; og < D_OUT / 4; ++og) {
    float a0 = b2[og * 4 + 0], a1 = b2[og * 4 + 1];
    float a2 = b2[og * 4 + 2], a3 = b2[og * 4 + 3];
#pragma unroll
    for (int j = 0; j < D_HID; ++j) {
      const float* w = W2 + (size_t)j * D_OUT + og * 4;  // uniform
      float hj = h[j];
      a0 = fmaf(hj, w[0], a0);
      a1 = fmaf(hj, w[1], a1);
      a2 = fmaf(hj, w[2], a2);
      a3 = fmaf(hj, w[3], a3);
    }
    if (n < N_NODES) {
      float4 r = make_float4(a0, a1, a2, a3);
      ((float4*)(x0 + (size_t)n * D_OUT))[og] = r;
    }
  }
}

// ---------------- CSR build ----------------
__global__ __launch_bounds__(256) void hist_kernel(
    const int* __restrict__ row, int* __restrict__ counts)
{
  int e = blockIdx.x * 256 + threadIdx.x;
  if (e < N_EDGES) atomicAdd(&counts[row[e]], 1);
}

__global__ __launch_bounds__(256) void scan1_kernel(
    const int* __restrict__ cnt, int* __restrict__ part, int* __restrict__ bsum)
{
  __shared__ int lds[SCAN_T];
  int t = threadIdx.x;
  int base = blockIdx.x * SCAN_B + t * SCAN_E;
  int v[SCAN_E];
  int s = 0;
#pragma unroll
  for (int u = 0; u < SCAN_E; ++u) {
    int i = base + u;
    int x = (i < N_NODES) ? cnt[i] : 0;
    v[u] = s;          // thread-local exclusive prefix
    s += x;
  }
  lds[t] = s;
  __syncthreads();
  for (int off = 1; off < SCAN_T; off <<= 1) {
    int add = (t >= off) ? lds[t - off] : 0;
    __syncthreads();
    lds[t] += add;
    __syncthreads();
  }
  int excl = lds[t] - s;
  if (t == SCAN_T - 1) bsum[blockIdx.x] = lds[SCAN_T - 1];
#pragma unroll
  for (int u = 0; u < SCAN_E; ++u) {
    int i = base + u;
    if (i < N_NODES) part[i] = excl + v[u];
  }
}

__global__ __launch_bounds__(256) void scan2_kernel(int* __restrict__ bsum, int nb)
{
  __shared__ int lds[SCAN_T];
  int t = threadIdx.x;
  int x = (t < nb) ? bsum[t] : 0;
  lds[t] = x;
  __syncthreads();
  for (int off = 1; off < SCAN_T; off <<= 1) {
    int add = (t >= off) ? lds[t - off] : 0;
    __syncthreads();
    lds[t] += add;
    __syncthreads();
  }
  if (t < nb) bsum[t] = lds[t] - x;   // exclusive
  if (t == nb - 1) bsum[nb] = lds[t]; // total
}

__global__ __launch_bounds__(256) void scan3_kernel(
    int* __restrict__ part /*row_ptr*/, int* __restrict__ fill,
    const int* __restrict__ bsum, int nb)
{
  int t = threadIdx.x;
  int off = bsum[blockIdx.x];
  int base = blockIdx.x * SCAN_B + t * SCAN_E;
#pragma unroll
  for (int u = 0; u < SCAN_E; ++u) {
    int i = base + u;
    if (i < N_NODES) { int v = part[i] + off; part[i] = v; fill[i] = v; }
  }
  if (blockIdx.x == 0 && t == 0) part[N_NODES] = bsum[nb];
}

__global__ __launch_bounds__(256) void scatter_kernel(
    const int* __restrict__ row, const int* __restrict__ col,
    const float* __restrict__ vals, int* __restrict__ fill,
    int* __restrict__ col_s, float* __restrict__ val_s)
{
  int e = blockIdx.x * 256 + threadIdx.x;
  if (e < N_EDGES) {
    int r = row[e];
    int p = atomicAdd(&fill[r], 1);
    col_s[p] = col[e];
    val_s[p] = vals[e];
  }
}

// ---------------- propagation: xout = 0.9 * (A @ xin) + 0.1 * x0 ----------------
// 32 lanes (half-wave) per row; lane = output channel. Gather of
// xin[col][0:32] is one coalesced 128B read. No atomics.
__global__ __launch_bounds__(256) void spmm_kernel(
    const int* __restrict__ rp, const int* __restrict__ cs,
    const float* __restrict__ vs, const float* __restrict__ xin,
    const float* __restrict__ x0, float* __restrict__ xout)
{
  int gt = blockIdx.x * 256 + threadIdx.x;
  int r = gt >> 5;
  int c = gt & 31;
  if (r >= N_NODES) return;
  int e0 = rp[r], e1 = rp[r + 1];
  float acc = 0.f;
  int e = e0;
  for (; e + 1 < e1; e += 2) {   // 2-edge unroll for MLP (two gathers in flight)
    int c0 = cs[e], c1 = cs[e + 1];
    float v0 = vs[e], v1 = vs[e + 1];
    acc = fmaf(v0, xin[(size_t)c0 * D_OUT + c], acc);
    acc = fmaf(v1, xin[(size_t)c1 * D_OUT + c], acc);
  }
  if (e < e1) acc = fmaf(vs[e], xin[(size_t)cs[e] * D_OUT + c], acc);
  xout[(size_t)r * D_OUT + c] = 0.9f * acc + 0.1f * x0[(size_t)r * D_OUT + c];
}

extern "C" void kernel_launch(void* const* d_in, const int* in_sizes, int n_in,
                              void* d_out, int out_size, void* d_ws, size_t ws_size,
                              hipStream_t stream) {
  const float* F     = (const float*)d_in[0];
  const int*   row   = (const int*)  d_in[1];
  const int*   col   = (const int*)  d_in[2];
  const float* evals = (const float*)d_in[3];
  const float* W1    = (const float*)d_in[4];
  const float* b1    = (const float*)d_in[5];
  const float* W2    = (const float*)d_in[6];
  const float* b2    = (const float*)d_in[7];
  float* out = (float*)d_out;

  // workspace layout (all offsets 256B-aligned); total ~39.3 MB
  char* w = (char*)d_ws;
  float* x0      = (float*)(w);                 // 12,800,000 B
  float* P       = (float*)(w + 12800000);      // 12,800,000 B
  int*   row_ptr = (int*)  (w + 25600000);      //    400,128 B  (N+1 ints)
  int*   fill    = (int*)  (w + 26000128);      //    400,128 B
  int*   col_s   = (int*)  (w + 26400256);      //  6,400,000 B
  float* val_s   = (float*)(w + 32800256);      //  6,400,000 B
  int*   bsum    = (int*)  (w + 39200256);      //      4,096 B

  // 1) MLP head -> x0
  mlp_kernel<<<(N_NODES + 255) / 256, 256, 0, stream>>>(F, W1, b1, W2, b2, x0);

  // 2) CSR build (every call; inputs are restored before each timed launch)
  hipMemsetAsync(fill, 0, (size_t)N_NODES * 4, stream);
  hist_kernel<<<(N_EDGES + 255) / 256, 256, 0, stream>>>(row, fill);
  scan1_kernel<<<NB1, SCAN_T, 0, stream>>>(fill, row_ptr, bsum);
  scan2_kernel<<<1, SCAN_T, 0, stream>>>(bsum, NB1);
  scan3_kernel<<<NB1, SCAN_T, 0, stream>>>(row_ptr, fill, bsum, NB1);
  scatter_kernel<<<(N_EDGES + 255) / 256, 256, 0, stream>>>(row, col, evals,
                                                            fill, col_s, val_s);

  // 3) 10 propagation rounds, ping-pong P <-> d_out; final lands in d_out
  for (int i = 0; i < NPROP; ++i) {
    const float* xin = (i == 0) ? x0 : ((i & 1) ? P : out);
    float* xout = (i & 1) ? out : P;
    spmm_kernel<<<(N_NODES * 32 + 255) / 256, 256, 0, stream>>>(
        row_ptr, col_s, val_s, xin, x0, xout);
  }
}